// Round 9
// baseline (259.035 us; speedup 1.0000x reference)
//
#include <hip/hip_runtime.h>
#include <hip/hip_fp16.h>

// ---------------------------------------------------------------------------
// CrowdGNN: 2-layer GCN, N=500k nodes, E=8M edges (+ implicit self loops).
// Round-9: agg kernels (deg/layer1/layer2, ~50us each) are LATENCY-bound
// (VALUBusy 2%, 1.3TB/s effective, occ 45%). Fixes:
//  - 8-wide slot unroll: 4x16B slot loads + 8 independent gathers in flight.
//  - integer fast path: slot carries w as q11 fixed (u32 field); y table is
//    short4 q11. deg = raw ds_add_u32 of wq (no cvt); layer1 contribution =
//    wq*yq (16x16 int mul, exact, == q22 acc scale) -> native int LDS atomic.
//    Shorter gather->atomic dep chains, no f2i/fmul per channel.
// Precision: eps_w=2^-12*|y|, eps_y=2^-12 -> ~1-2e-3 agg error, under the
// 1.98e-2 threshold. Overflow: |acc1|<=265*2^22<2^31; deg sum<2^17; ok.
// Partition unchanged from round 8 (bin-sorted LDS staging, 83.5us).
// ---------------------------------------------------------------------------

typedef unsigned long long u64;
typedef long long ll2 __attribute__((ext_vector_type(2)));
typedef short s4 __attribute__((ext_vector_type(4)));

#define NPB_SHIFT 9
#define NPB 512
#define MAX_BINS 1024
#define PART_THREADS 1024
#define PART_EPT 4
#define PART_CHUNK (PART_THREADS * PART_EPT)   // 4096 edges per block
#define AGG_THREADS 512

#define Q11        2048.0f
#define INV11      (1.0f / 2048.0f)
#define A1_INV     (1.0f / 4194304.0f)   // q22 = q11*q11
#define A2_SCALE   1048576.0f            // 2^20
#define A2_INV     (1.0f / 1048576.0f)

// Detect int64 vs int32 edge_index: int64 values < 2^31 => odd words all zero.
__global__ __launch_bounds__(1024)
void k_detect(const unsigned int* __restrict__ idx_words, int nCheck, int* flag) {
    __shared__ int cnt;
    if (threadIdx.x == 0) cnt = 0;
    __syncthreads();
    int local = 0;
    for (int i = threadIdx.x; i < nCheck; i += blockDim.x)
        local += (idx_words[2 * i + 1] != 0u) ? 1 : 0;
    if (local) atomicAdd(&cnt, local);
    __syncthreads();
    if (threadIdx.x == 0) *flag = (cnt < 8) ? 1 : 0;
}

__global__ __launch_bounds__(256)
void k_zero(int* __restrict__ p, int n) {
    int i = blockIdx.x * blockDim.x + threadIdx.x;
    if (i < n) p[i] = 0;
}

// Bin-sorted-staging partition. Block = 1024 thr x 4 edges = 4096 edges.
__global__ __launch_bounds__(PART_THREADS)
void k_partition(const void* __restrict__ idx, const float* __restrict__ ew,
                 int* __restrict__ gCnt, u64* __restrict__ slots,
                 int E, int B, int cap, const int* __restrict__ flag) {
    __shared__ int lcnt[MAX_BINS];
    __shared__ int lbase[MAX_BINS];
    __shared__ int lstart[MAX_BINS];
    __shared__ u64 sPay[PART_CHUNK];
    __shared__ unsigned sAddr[PART_CHUNK];
    __shared__ int waveSum[PART_THREADS / 64];

    const bool is64 = (*flag != 0);
    const int tid = threadIdx.x;
    for (int i = tid; i < MAX_BINS; i += PART_THREADS) lcnt[i] = 0;
    __syncthreads();

    const int base_e = blockIdx.x * PART_CHUNK;
    const int nValid = min(PART_CHUNK, E - base_e);

    u64 pay[PART_EPT];
    int bin_[PART_EPT], r_[PART_EPT];
#pragma unroll
    for (int i = 0; i < PART_EPT; ++i) {
        int e = base_e + i * PART_THREADS + tid;
        bin_[i] = -1;
        if (e < E) {
            int s, d;
            if (is64) {
                const long long* p = (const long long*)idx;
                s = (int)__builtin_nontemporal_load(p + e);
                d = (int)__builtin_nontemporal_load(p + (long long)E + e);
            } else {
                const int* p = (const int*)idx;
                s = __builtin_nontemporal_load(p + e);
                d = __builtin_nontemporal_load(p + E + e);
            }
            float w = __builtin_nontemporal_load(ew + e);
            int bin = d >> NPB_SHIFT;
            unsigned wq = min((unsigned)__float2int_rn(w * Q11), 2047u);
            unsigned pk = ((unsigned)(d & (NPB - 1)) << 23) | (unsigned)s;
            pay[i] = ((u64)wq << 32) | pk;
            bin_[i] = bin;
            r_[i] = atomicAdd(&lcnt[bin], 1);   // native ds_add, block-local rank
        }
    }
    __syncthreads();

    // Exclusive prefix scan of lcnt -> lstart; global base -> lbase.
    {
        const int lane = tid & 63, wid = tid >> 6;
        const int v = lcnt[tid];
        int inc = v;
#pragma unroll
        for (int off = 1; off < 64; off <<= 1) {
            int t = __shfl_up(inc, off, 64);
            if (lane >= off) inc += t;
        }
        if (lane == 63) waveSum[wid] = inc;
        __syncthreads();
        if (wid == 0) {
            const int NW = PART_THREADS / 64;
            int wv = (lane < NW) ? waveSum[lane] : 0;
            int winc = wv;
#pragma unroll
            for (int off = 1; off < NW; off <<= 1) {
                int t = __shfl_up(winc, off, 64);
                if (lane >= off) winc += t;
            }
            if (lane < NW) waveSum[lane] = winc - wv;  // exclusive wave offsets
        }
        __syncthreads();
        lstart[tid] = inc - v + waveSum[wid];
        lbase[tid] = (v > 0 && tid < B) ? atomicAdd(&gCnt[tid], v) : 0;
    }
    __syncthreads();

    // Stage in bin-sorted order.
#pragma unroll
    for (int i = 0; i < PART_EPT; ++i) {
        if (bin_[i] >= 0) {
            int si = lstart[bin_[i]] + r_[i];
            long long pos = (long long)lbase[bin_[i]] + r_[i];
            sPay[si] = pay[i];
            sAddr[si] = (pos < cap)
                      ? (unsigned)((long long)bin_[i] * cap + pos)
                      : 0xFFFFFFFFu;   // overflow guard (never expected)
        }
    }
    __syncthreads();

    // Coalesced store: consecutive k -> consecutive addresses within bin runs.
    for (int k = tid; k < nValid; k += PART_THREADS) {
        unsigned a = sAddr[k];
        if (a != 0xFFFFFFFFu) slots[a] = sPay[k];
    }
}

// 8-wide slot fetch; OOB entries -> 0 (wq=0 => no-op adds).
__device__ __forceinline__ void load8(const u64* __restrict__ sp, int j, int c,
                                      u64* __restrict__ v) {
    if (j + 7 < c) {
#pragma unroll
        for (int q = 0; q < 4; ++q) {
            ll2 t = *((const ll2*)(sp + j) + q);
            v[2 * q]     = (u64)t.x;
            v[2 * q + 1] = (u64)t.y;
        }
    } else {
#pragma unroll
        for (int q = 0; q < 8; ++q)
            v[q] = (j + q < c) ? sp[j + q] : 0ULL;
    }
}

// Per-bin: deg[n] = 1 + sum w; dinv = rsqrt(deg); y[n] = q11(x[n]*dinv).
__global__ __launch_bounds__(AGG_THREADS, 4)
void k_deg_dinv(const u64* __restrict__ slots, const int* __restrict__ gCnt,
                const float4* __restrict__ x, float* __restrict__ dinv,
                s4* __restrict__ y, int N, int cap) {
    __shared__ int degLds[NPB];
    const int b = blockIdx.x;
    for (int t = threadIdx.x; t < NPB; t += AGG_THREADS) degLds[t] = 0;
    __syncthreads();
    const int c = min(gCnt[b], cap);
    const u64* sp = slots + (size_t)b * cap;
    const int CH = AGG_THREADS * 8;
    for (int base = 0; base < c; base += CH) {
        int j = base + (threadIdx.x << 3);
        u64 v[8];
        load8(sp, j, c, v);
#pragma unroll
        for (int q = 0; q < 8; ++q)
            atomicAdd(&degLds[((unsigned)v[q]) >> 23], (int)(v[q] >> 32));
    }
    __syncthreads();
    for (int t = threadIdx.x; t < NPB; t += AGG_THREADS) {
        int n = (b << NPB_SHIFT) + t;
        if (n < N) {
            float di = rsqrtf(1.0f + (float)degLds[t] * INV11);
            dinv[n] = di;
            float4 xv = x[n];
            s4 q;
            q.x = (short)__float2int_rn(xv.x * di * Q11);
            q.y = (short)__float2int_rn(xv.y * di * Q11);
            q.z = (short)__float2int_rn(xv.z * di * Q11);
            q.w = (short)__float2int_rn(xv.w * di * Q11);
            y[n] = q;
        }
    }
}

// Per-bin layer1 aggregation + fused MLP: z[n] = dinv[n]*MLP(di*(y[n]+sum w*y[s]))
// Pure-integer edge path: contribution = wq * yq  (q11*q11 = q22, exact).
__global__ __launch_bounds__(AGG_THREADS, 4)
void k_layer1(const u64* __restrict__ slots, const int* __restrict__ gCnt,
              const float* __restrict__ dinv, const s4* __restrict__ yq,
              const float* __restrict__ W1, const float* __restrict__ b1,
              const float* __restrict__ W2, float* __restrict__ z,
              int N, int cap) {
    __shared__ int acc[NPB][5];   // stride 5 -> 32-bank spread
    __shared__ float dLds[NPB];
    __shared__ float sW1[64], sb1[16], sW2[16];
    if (threadIdx.x < 64) sW1[threadIdx.x] = W1[threadIdx.x];
    if (threadIdx.x < 16) {
        sb1[threadIdx.x] = b1[threadIdx.x];
        sW2[threadIdx.x] = W2[threadIdx.x];
    }
    const int b = blockIdx.x;
    for (int t = threadIdx.x; t < NPB; t += AGG_THREADS) {
        acc[t][0] = acc[t][1] = acc[t][2] = acc[t][3] = 0;
        int n = (b << NPB_SHIFT) + t;
        dLds[t] = (n < N) ? dinv[n] : 0.0f;
    }
    __syncthreads();
    const int c = min(gCnt[b], cap);
    const u64* sp = slots + (size_t)b * cap;
    const int CH = AGG_THREADS * 8;
    for (int base = 0; base < c; base += CH) {
        int j = base + (threadIdx.x << 3);
        u64 v[8];
        load8(sp, j, c, v);
        s4 g[8];
#pragma unroll
        for (int q = 0; q < 8; ++q) {
            int src = min((int)((unsigned)v[q] & 0x7FFFFF), N - 1);
            g[q] = yq[src];            // 8 independent gathers in flight
        }
#pragma unroll
        for (int q = 0; q < 8; ++q) {
            int wq = (int)(v[q] >> 32);
            int dl = (int)(((unsigned)v[q]) >> 23);
            atomicAdd(&acc[dl][0], wq * (int)g[q].x);
            atomicAdd(&acc[dl][1], wq * (int)g[q].y);
            atomicAdd(&acc[dl][2], wq * (int)g[q].z);
            atomicAdd(&acc[dl][3], wq * (int)g[q].w);
        }
    }
    __syncthreads();
    for (int t = threadIdx.x; t < NPB; t += AGG_THREADS) {
        int n = (b << NPB_SHIFT) + t;
        if (n >= N) continue;
        float di = dLds[t];
        s4 yv = yq[n];
        float ax = di * ((float)yv.x * INV11 + (float)acc[t][0] * A1_INV);
        float ay = di * ((float)yv.y * INV11 + (float)acc[t][1] * A1_INV);
        float az = di * ((float)yv.z * INV11 + (float)acc[t][2] * A1_INV);
        float aw = di * ((float)yv.w * INV11 + (float)acc[t][3] * A1_INV);
        float sacc = 0.0f;
#pragma unroll
        for (int k = 0; k < 16; ++k) {
            float h = ax * sW1[k] + ay * sW1[16 + k] + az * sW1[32 + k]
                    + aw * sW1[48 + k] + sb1[k];
            sacc += fmaxf(h, 0.0f) * sW2[k];
        }
        z[n] = sacc * di;
    }
}

// Per-bin layer2: out[n] = di*(z[n] + sum w*z[s]) + b2
__global__ __launch_bounds__(AGG_THREADS, 4)
void k_layer2(const u64* __restrict__ slots, const int* __restrict__ gCnt,
              const float* __restrict__ dinv, const float* __restrict__ z,
              const float* __restrict__ b2, float* __restrict__ out,
              int N, int cap) {
    __shared__ int accs[NPB];
    __shared__ float dLds[NPB];
    const int b = blockIdx.x;
    for (int t = threadIdx.x; t < NPB; t += AGG_THREADS) {
        accs[t] = 0;
        int n = (b << NPB_SHIFT) + t;
        dLds[t] = (n < N) ? dinv[n] : 0.0f;
    }
    __syncthreads();
    const int c = min(gCnt[b], cap);
    const u64* sp = slots + (size_t)b * cap;
    const int CH = AGG_THREADS * 8;
    for (int base = 0; base < c; base += CH) {
        int j = base + (threadIdx.x << 3);
        u64 v[8];
        load8(sp, j, c, v);
        float zf[8];
#pragma unroll
        for (int q = 0; q < 8; ++q) {
            int src = min((int)((unsigned)v[q] & 0x7FFFFF), N - 1);
            zf[q] = z[src];            // 8 independent gathers
        }
#pragma unroll
        for (int q = 0; q < 8; ++q) {
            // w*z * 2^20 = wq * z * 2^9
            float fx = (float)(int)(v[q] >> 32) * zf[q] * 512.0f;
            atomicAdd(&accs[((unsigned)v[q]) >> 23], __float2int_rn(fx));
        }
    }
    __syncthreads();
    const float bb2 = b2[0];
    for (int t = threadIdx.x; t < NPB; t += AGG_THREADS) {
        int n = (b << NPB_SHIFT) + t;
        if (n < N) out[n] = dLds[t] * (z[n] + (float)accs[t] * A2_INV) + bb2;
    }
}

// ------------------------- fallback (round-1) path -------------------------
__global__ __launch_bounds__(256)
void k_init(float* __restrict__ deg, int N) {
    int i = blockIdx.x * blockDim.x + threadIdx.x;
    if (i < N) deg[i] = 1.0f;
}

__global__ __launch_bounds__(256)
void k_deg(const void* __restrict__ idx, const float* __restrict__ ew,
           float* __restrict__ deg, int E, const int* __restrict__ flag) {
    const bool is64 = (*flag != 0);
    const int stride = gridDim.x * blockDim.x;
    for (int e = blockIdx.x * blockDim.x + threadIdx.x; e < E; e += stride) {
        int d = is64 ? (int)((const long long*)idx)[(long long)E + e]
                     : ((const int*)idx)[E + e];
        atomicAdd(deg + d, ew[e]);
    }
}

__global__ __launch_bounds__(256)
void k_dinv_accx(float* __restrict__ deg_dinv, const float4* __restrict__ x,
                 float4* __restrict__ accx, int N) {
    int n = blockIdx.x * blockDim.x + threadIdx.x;
    if (n >= N) return;
    float dg = deg_dinv[n];
    float di = (dg > 0.0f) ? rsqrtf(dg) : 0.0f;
    deg_dinv[n] = di;
    float sn = di * di;
    float4 xv = x[n];
    accx[n] = make_float4(xv.x * sn, xv.y * sn, xv.z * sn, xv.w * sn);
}

__global__ __launch_bounds__(256)
void k_scatter1(const void* __restrict__ idx, const float* __restrict__ ew,
                const float* __restrict__ dinv, const float4* __restrict__ x,
                float* __restrict__ accx, int E, const int* __restrict__ flag) {
    const bool is64 = (*flag != 0);
    const int stride = gridDim.x * blockDim.x;
    for (int e = blockIdx.x * blockDim.x + threadIdx.x; e < E; e += stride) {
        int s, d;
        if (is64) {
            const long long* p = (const long long*)idx;
            s = (int)p[e]; d = (int)p[(long long)E + e];
        } else {
            const int* p = (const int*)idx;
            s = p[e]; d = p[E + e];
        }
        float nm = dinv[s] * ew[e] * dinv[d];
        float4 xv = x[s];
        float* dp = accx + (size_t)d * 4;
        atomicAdd(dp + 0, nm * xv.x);
        atomicAdd(dp + 1, nm * xv.y);
        atomicAdd(dp + 2, nm * xv.z);
        atomicAdd(dp + 3, nm * xv.w);
    }
}

__global__ __launch_bounds__(256)
void k_node2(const float4* __restrict__ accx, const float* __restrict__ dinv,
             const float* __restrict__ W1, const float* __restrict__ b1,
             const float* __restrict__ W2, const float* __restrict__ b2,
             float* __restrict__ s2, float* __restrict__ out, int N) {
    __shared__ float sW1[64], sb1[16], sW2[16];
    if (threadIdx.x < 64) sW1[threadIdx.x] = W1[threadIdx.x];
    if (threadIdx.x < 16) {
        sb1[threadIdx.x] = b1[threadIdx.x];
        sW2[threadIdx.x] = W2[threadIdx.x];
    }
    __syncthreads();
    int n = blockIdx.x * blockDim.x + threadIdx.x;
    if (n >= N) return;
    float bb2 = b2[0];
    float4 a = accx[n];
    float acc = 0.0f;
#pragma unroll
    for (int k = 0; k < 16; ++k) {
        float h = a.x * sW1[k] + a.y * sW1[16 + k] + a.z * sW1[32 + k]
                + a.w * sW1[48 + k] + sb1[k];
        acc += fmaxf(h, 0.0f) * sW2[k];
    }
    s2[n] = acc;
    float di = dinv[n];
    out[n] = acc * di * di + bb2;
}

__global__ __launch_bounds__(256)
void k_scatter2(const void* __restrict__ idx, const float* __restrict__ ew,
                const float* __restrict__ dinv, const float* __restrict__ s2,
                float* __restrict__ out, int E, const int* __restrict__ flag) {
    const bool is64 = (*flag != 0);
    const int stride = gridDim.x * blockDim.x;
    for (int e = blockIdx.x * blockDim.x + threadIdx.x; e < E; e += stride) {
        int s, d;
        if (is64) {
            const long long* p = (const long long*)idx;
            s = (int)p[e]; d = (int)p[(long long)E + e];
        } else {
            const int* p = (const int*)idx;
            s = p[e]; d = p[E + e];
        }
        float nm = dinv[s] * ew[e] * dinv[d];
        atomicAdd(out + d, nm * s2[s]);
    }
}

// ---------------------------------------------------------------------------
extern "C" void kernel_launch(void* const* d_in, const int* in_sizes, int n_in,
                              void* d_out, int out_size, void* d_ws, size_t ws_size,
                              hipStream_t stream) {
    const float* x   = (const float*)d_in[0];
    const void*  eix = d_in[1];
    const float* ew  = (const float*)d_in[2];
    const float* W1  = (const float*)d_in[3];
    const float* b1  = (const float*)d_in[4];
    const float* W2  = (const float*)d_in[5];
    const float* b2  = (const float*)d_in[6];
    float* out = (float*)d_out;

    const int N = in_sizes[0] / 4;   // x is [N,4]
    const int E = in_sizes[2];       // edge_weight is [E]

    const int B = (N + NPB - 1) >> NPB_SHIFT;
    int cap = (E / B + 2048 + 7) & ~7;   // mean + ~23 sigma, multiple of 8
    const int nCheck = (E < 65536) ? E : 65536;

    // ws: y [N s4=8B] | slots [B*cap u64] | gCnt [B] | dinv [N] | z [N] | flag
    size_t need = (size_t)N * 8 + (size_t)B * cap * 8
                + (size_t)B * 4 + (size_t)N * 8 + 256;

    // u32 slot-address space check for the staged-store partition
    bool addr32ok = ((long long)B * cap) < 0xFFFFFFFFLL;

    if (B <= MAX_BINS && N < (1 << 23) && ws_size >= need && addr32ok) {
        s4* y = (s4*)d_ws;
        u64* slots = (u64*)(y + N);
        int*   gCnt = (int*)(slots + (size_t)B * cap);
        float* dinv = (float*)(gCnt + B);
        float* z    = dinv + N;
        int*   flag = (int*)(z + N);

        const int part_blocks = (E + PART_CHUNK - 1) / PART_CHUNK;

        k_zero<<<(B + 255) / 256, 256, 0, stream>>>(gCnt, B);
        k_detect<<<1, 1024, 0, stream>>>((const unsigned int*)eix, nCheck, flag);
        k_partition<<<part_blocks, PART_THREADS, 0, stream>>>(eix, ew, gCnt, slots,
                                                              E, B, cap, flag);
        k_deg_dinv<<<B, AGG_THREADS, 0, stream>>>(slots, gCnt, (const float4*)x,
                                                  dinv, y, N, cap);
        k_layer1<<<B, AGG_THREADS, 0, stream>>>(slots, gCnt, dinv, y, W1, b1, W2,
                                                z, N, cap);
        k_layer2<<<B, AGG_THREADS, 0, stream>>>(slots, gCnt, dinv, z, b2, out, N, cap);
    } else {
        // fallback: direct atomic scatter (round-1)
        const int nb_n = (N + 255) / 256;
        const int nb_e = min((E + 255) / 256, 16384);
        float* deg  = (float*)d_ws;
        float* accx = deg + N;
        float* s2   = accx + (size_t)4 * N;
        int*   flag = (int*)(s2 + N);

        k_init<<<nb_n, 256, 0, stream>>>(deg, N);
        k_detect<<<1, 1024, 0, stream>>>((const unsigned int*)eix, nCheck, flag);
        k_deg<<<nb_e, 256, 0, stream>>>(eix, ew, deg, E, flag);
        k_dinv_accx<<<nb_n, 256, 0, stream>>>(deg, (const float4*)x, (float4*)accx, N);
        k_scatter1<<<nb_e, 256, 0, stream>>>(eix, ew, deg, (const float4*)x, accx, E, flag);
        k_node2<<<nb_n, 256, 0, stream>>>((const float4*)accx, deg, W1, b1, W2, b2, s2, out, N);
        k_scatter2<<<nb_e, 256, 0, stream>>>(eix, ew, deg, s2, out, E, flag);
    }
}